// Round 1
// baseline (1406.939 us; speedup 1.0000x reference)
//
#include <hip/hip_runtime.h>

#define NN 50000
#define NE 800000
#define NG 64
#define DD 128
#define NL 3

// ---------------- CSR build ----------------
__global__ __launch_bounds__(256) void hist_kernel(const int* __restrict__ dst,
                                                   int* __restrict__ counts, int n) {
  int e = blockIdx.x * 256 + threadIdx.x;
  if (e < n) atomicAdd(&counts[dst[e]], 1);
}

__global__ __launch_bounds__(1024) void scan_kernel(const int* __restrict__ in,
                                                    int* __restrict__ out, int n) {
  __shared__ int sdata[1024];
  __shared__ int carry;
  if (threadIdx.x == 0) carry = 0;
  __syncthreads();
  for (int base = 0; base < n; base += 1024) {
    int i = base + threadIdx.x;
    int v = (i < n) ? in[i] : 0;
    sdata[threadIdx.x] = v;
    __syncthreads();
    for (int off = 1; off < 1024; off <<= 1) {
      int t = (threadIdx.x >= off) ? sdata[threadIdx.x - off] : 0;
      __syncthreads();
      sdata[threadIdx.x] += t;
      __syncthreads();
    }
    int incl = sdata[threadIdx.x];
    int c = carry;
    if (i < n) out[i] = c + incl - v;  // exclusive
    int tot = sdata[1023];
    __syncthreads();
    if (threadIdx.x == 0) carry = c + tot;
    __syncthreads();
  }
  if (threadIdx.x == 0) out[n] = carry;
}

__global__ __launch_bounds__(256) void copy_int_kernel(const int* __restrict__ in,
                                                       int* __restrict__ out, int n) {
  int i = blockIdx.x * 256 + threadIdx.x;
  if (i < n) out[i] = in[i];
}

__global__ __launch_bounds__(256) void fill_kernel(const int* __restrict__ src,
                                                   const int* __restrict__ dst,
                                                   int* __restrict__ cursor,
                                                   int* __restrict__ col, int n) {
  int e = blockIdx.x * 256 + threadIdx.x;
  if (e < n) {
    int p = atomicAdd(&cursor[dst[e]], 1);
    col[p] = src[e];
  }
}

// ---------------- aggregation: y = x + segment_sum(x[src] -> dst) ----------------
// 32 lanes per node (float4 per lane = 128 floats), 8 nodes per 256-thread block.
__global__ __launch_bounds__(256) void agg_y_kernel(const float* __restrict__ X,
                                                    const int* __restrict__ rowptr,
                                                    const int* __restrict__ col,
                                                    float* __restrict__ Y) {
  int node = blockIdx.x * 8 + (threadIdx.x >> 5);
  int lane = threadIdx.x & 31;
  const float4* X4 = reinterpret_cast<const float4*>(X);
  float4 a = X4[(size_t)node * 32 + lane];  // self term (eps=0)
  int s = rowptr[node], e = rowptr[node + 1];
  for (int j = s; j < e; ++j) {
    int src = col[j];
    float4 v = X4[(size_t)src * 32 + lane];
    a.x += v.x; a.y += v.y; a.z += v.z; a.w += v.w;
  }
  reinterpret_cast<float4*>(Y)[(size_t)node * 32 + lane] = a;
}

// ---------------- GEMM [nrows x 128] @ [128 x 128] + bias + activation ----------------
// act: 0 = BN(eval)+ReLU, 1 = ReLU, 2 = LeakyReLU(0.01)
__global__ __launch_bounds__(256) void gemm_act_kernel(
    const float* __restrict__ X, const float* __restrict__ W,
    const float* __restrict__ bias, const float* __restrict__ bn_g,
    const float* __restrict__ bn_b, const float* __restrict__ bn_m,
    const float* __restrict__ bn_v, float* __restrict__ out, int nrows, int act) {
  __shared__ float ylds[32][DD];
  int row0 = blockIdx.x * 32;
  const float4* X4 = reinterpret_cast<const float4*>(X);
  for (int t = threadIdx.x; t < 1024; t += 256) {
    int r = t >> 5, c = t & 31;
    float4 v = make_float4(0.f, 0.f, 0.f, 0.f);
    if (row0 + r < nrows) v = X4[(size_t)(row0 + r) * 32 + c];
    reinterpret_cast<float4*>(&ylds[r][0])[c] = v;
  }
  __syncthreads();
  int c4 = threadIdx.x & 31;           // column group: cols c4*4 .. c4*4+3
  int rg = (threadIdx.x >> 5) << 2;    // rows rg .. rg+3
  const float4* W4 = reinterpret_cast<const float4*>(W);
  float a[4][4];
#pragma unroll
  for (int r = 0; r < 4; r++)
#pragma unroll
    for (int j = 0; j < 4; j++) a[r][j] = 0.f;
#pragma unroll 4
  for (int k = 0; k < DD; ++k) {
    float4 w = W4[k * 32 + c4];
#pragma unroll
    for (int r = 0; r < 4; r++) {
      float y = ylds[rg + r][k];
      a[r][0] += w.x * y; a[r][1] += w.y * y; a[r][2] += w.z * y; a[r][3] += w.w * y;
    }
  }
  int cbase = c4 * 4;
  float bs[4], sc[4], bb2[4], mm[4];
#pragma unroll
  for (int j = 0; j < 4; j++) { bs[j] = bias[cbase + j]; sc[j] = 1.f; bb2[j] = 0.f; mm[j] = 0.f; }
  if (act == 0) {
#pragma unroll
    for (int j = 0; j < 4; j++) {
      sc[j]  = bn_g[cbase + j] * rsqrtf(bn_v[cbase + j] + 1e-5f);
      bb2[j] = bn_b[cbase + j];
      mm[j]  = bn_m[cbase + j];
    }
  }
#pragma unroll
  for (int r = 0; r < 4; r++) {
    int row = row0 + rg + r;
    if (row < nrows) {
      float4 o;
      float* op = reinterpret_cast<float*>(&o);
#pragma unroll
      for (int j = 0; j < 4; j++) {
        float v = a[r][j] + bs[j];
        if (act == 0)      { v = (v - mm[j]) * sc[j] + bb2[j]; v = fmaxf(v, 0.f); }
        else if (act == 1) { v = fmaxf(v, 0.f); }
        else               { v = v > 0.f ? v : 0.01f * v; }
        op[j] = v;
      }
      reinterpret_cast<float4*>(out)[(size_t)row * 32 + c4] = o;
    }
  }
}

// ---------------- pooling: z[batch[r]][coloff + f] += x[r][f] (batch sorted) ----------------
__global__ __launch_bounds__(128) void pool_kernel(const float* __restrict__ X,
                                                   const int* __restrict__ batch,
                                                   float* __restrict__ z, int coloff) {
  int f = threadIdx.x;
  int r0 = blockIdx.x * 128;
  int rend = r0 + 128; if (rend > NN) rend = NN;
  if (r0 >= NN) return;
  float acc = 0.f;
  int cur = batch[r0];
  for (int r = r0; r < rend; ++r) {
    int g = batch[r];
    if (g != cur) {
      atomicAdd(&z[(size_t)cur * (2 * DD * NL) + coloff + f], acc);
      acc = 0.f; cur = g;
    }
    acc += X[(size_t)r * DD + f];
  }
  atomicAdd(&z[(size_t)cur * (2 * DD * NL) + coloff + f], acc);
}

// ---------------- head: relu(z @ Wf1 + bf1) @ Wf2 + bf2 ----------------
__global__ __launch_bounds__(128) void head_kernel(const float* __restrict__ z,
                                                   const float* __restrict__ Wf1,
                                                   const float* __restrict__ bf1,
                                                   const float* __restrict__ Wf2,
                                                   const float* __restrict__ bf2,
                                                   float* __restrict__ out) {
  int g = blockIdx.x, t = threadIdx.x;
  const float* zr = z + (size_t)g * (2 * DD * NL);
  float acc = bf1[t];
  for (int j = 0; j < 2 * DD * NL; ++j) acc += zr[j] * Wf1[(size_t)j * DD + t];
  float h = fmaxf(acc, 0.f);
  __shared__ float red[128];
  red[t] = h * Wf2[t];
  __syncthreads();
  for (int s = 64; s > 0; s >>= 1) {
    if (t < s) red[t] += red[t + s];
    __syncthreads();
  }
  if (t == 0) out[g] = red[0] + bf2[0];
}

extern "C" void kernel_launch(void* const* d_in, const int* in_sizes, int n_in,
                              void* d_out, int out_size, void* d_ws, size_t ws_size,
                              hipStream_t stream) {
  const float* x1   = (const float*)d_in[0];
  const float* x2   = (const float*)d_in[1];
  const float* W1c1 = (const float*)d_in[2];
  const float* b1c1 = (const float*)d_in[3];
  const float* bng  = (const float*)d_in[4];
  const float* bnb  = (const float*)d_in[5];
  const float* bnm  = (const float*)d_in[6];
  const float* bnv  = (const float*)d_in[7];
  const float* W2c1 = (const float*)d_in[8];
  const float* b2c1 = (const float*)d_in[9];
  const float* W1c2 = (const float*)d_in[10];
  const float* b1c2 = (const float*)d_in[11];
  const float* W2c2 = (const float*)d_in[12];
  const float* b2c2 = (const float*)d_in[13];
  const float* Wf1  = (const float*)d_in[14];
  const float* bf1  = (const float*)d_in[15];
  const float* Wf2  = (const float*)d_in[16];
  const float* bf2  = (const float*)d_in[17];
  const int* edge1  = (const int*)d_in[18];
  const int* edge2  = (const int*)d_in[19];
  const int* batch1 = (const int*)d_in[20];
  const int* batch2 = (const int*)d_in[21];

  char* ws = (char*)d_ws;
  const size_t NB = (size_t)NN * DD * sizeof(float);  // 25.6 MB
  float* bufA = (float*)(ws);
  float* bufB = (float*)(ws + NB);
  float* bufC = (float*)(ws + 2 * NB);
  size_t off = 3 * NB;
  int* rowptr = (int*)(ws + off); off += (((size_t)(NN + 1) * 4) + 255) & ~(size_t)255;
  int* cursor = (int*)(ws + off); off += (((size_t)NN * 4) + 255) & ~(size_t)255;
  int* col    = (int*)(ws + off); off += (size_t)NE * 4;
  float* z    = (float*)(ws + off); off += (size_t)NG * 2 * DD * NL * 4;
  (void)ws_size; (void)n_in; (void)in_sizes; (void)out_size;

  hipMemsetAsync(z, 0, (size_t)NG * 2 * DD * NL * 4, stream);

  for (int ch = 0; ch < 2; ++ch) {
    const int* edge   = ch == 0 ? edge1 : edge2;
    const int* batch  = ch == 0 ? batch1 : batch2;
    const float* x0   = ch == 0 ? x1 : x2;
    const float* W1   = ch == 0 ? W1c1 : W1c2;
    const float* b1   = ch == 0 ? b1c1 : b1c2;
    const float* W2   = ch == 0 ? W2c1 : W2c2;
    const float* b2   = ch == 0 ? b2c1 : b2c2;
    const int act1 = ch == 0 ? 0 : 1;  // ch1: BN+ReLU, ch2: ReLU
    const int act2 = ch == 0 ? 1 : 2;  // ch1: ReLU (leaky∘relu == relu), ch2: LeakyReLU

    // CSR by dst (edge list shared across the channel's 3 layers)
    hipMemsetAsync(cursor, 0, (size_t)NN * 4, stream);
    hist_kernel<<<NE / 256, 256, 0, stream>>>(edge + NE, cursor, NE);
    scan_kernel<<<1, 1024, 0, stream>>>(cursor, rowptr, NN);
    copy_int_kernel<<<(NN + 255) / 256, 256, 0, stream>>>(rowptr, cursor, NN);
    fill_kernel<<<NE / 256, 256, 0, stream>>>(edge, edge + NE, cursor, col, NE);

    for (int i = 0; i < NL; ++i) {
      const float* xc = (i == 0) ? x0 : bufA;
      agg_y_kernel<<<NN / 8, 256, 0, stream>>>(xc, rowptr, col, bufB);
      gemm_act_kernel<<<(NN + 31) / 32, 256, 0, stream>>>(
          bufB, W1 + (size_t)i * DD * DD, b1 + i * DD,
          bng + i * DD, bnb + i * DD, bnm + i * DD, bnv + i * DD,
          bufC, NN, act1);
      gemm_act_kernel<<<(NN + 31) / 32, 256, 0, stream>>>(
          bufC, W2 + (size_t)i * DD * DD, b2 + i * DD,
          bng, bnb, bnm, bnv, bufA, NN, act2);
      pool_kernel<<<(NN + 127) / 128, 128, 0, stream>>>(bufA, batch, z, ch * DD * NL + i * DD);
    }
  }
  head_kernel<<<NG, 128, 0, stream>>>(z, Wf1, bf1, Wf2, bf2, (float*)d_out);
}

// Round 2
// 1067.073 us; speedup vs baseline: 1.3185x; 1.3185x over previous
//
#include <hip/hip_runtime.h>

#define NN 50000
#define NE 800000
#define NG 64
#define DD 128
#define NL 3

typedef __attribute__((ext_vector_type(8))) short short8;
typedef __attribute__((ext_vector_type(4))) float f32x4;

__device__ inline unsigned short f2bf(float f) {
  unsigned int u = __float_as_uint(f);
  unsigned int r = (u + 0x7fffu + ((u >> 16) & 1u)) >> 16;
  return (unsigned short)r;
}
__device__ inline float bf2f(unsigned short h) {
  return __uint_as_float((unsigned int)h << 16);
}

// ---------------- fp32 -> bf16 convert (8 elems/thread) ----------------
__global__ __launch_bounds__(256) void cvt_bf16_kernel(const float* __restrict__ in,
                                                       unsigned short* __restrict__ out, int n8) {
  int i = blockIdx.x * 256 + threadIdx.x;
  if (i >= n8) return;
  const float4* in4 = reinterpret_cast<const float4*>(in);
  float4 a = in4[2 * i], b = in4[2 * i + 1];
  uint4 o;
  o.x = (unsigned int)f2bf(a.x) | ((unsigned int)f2bf(a.y) << 16);
  o.y = (unsigned int)f2bf(a.z) | ((unsigned int)f2bf(a.w) << 16);
  o.z = (unsigned int)f2bf(b.x) | ((unsigned int)f2bf(b.y) << 16);
  o.w = (unsigned int)f2bf(b.z) | ((unsigned int)f2bf(b.w) << 16);
  reinterpret_cast<uint4*>(out)[i] = o;
}

// ---------------- W [mat][k][c] fp32 -> WT [mat][c][k] bf16 ----------------
__global__ __launch_bounds__(256) void cvt_wt_kernel(const float* __restrict__ in,
                                                     unsigned short* __restrict__ out) {
  __shared__ float tile[32][33];
  int mat = blockIdx.z;
  int k0 = blockIdx.x * 32, c0 = blockIdx.y * 32;
  int tx = threadIdx.x & 31, ty = threadIdx.x >> 5;  // 8 rows per pass
  const float* ip = in + mat * 16384;
  unsigned short* op = out + mat * 16384;
#pragma unroll
  for (int rr = 0; rr < 32; rr += 8)
    tile[ty + rr][tx] = ip[(k0 + ty + rr) * 128 + (c0 + tx)];
  __syncthreads();
#pragma unroll
  for (int rr = 0; rr < 32; rr += 8)
    op[(c0 + ty + rr) * 128 + (k0 + tx)] = f2bf(tile[tx][ty + rr]);
}

// ---------------- CSR build ----------------
__global__ __launch_bounds__(256) void hist_kernel(const int* __restrict__ dst,
                                                   int* __restrict__ counts, int n) {
  int e = blockIdx.x * 256 + threadIdx.x;
  if (e < n) atomicAdd(&counts[dst[e]], 1);
}

__global__ __launch_bounds__(256) void scan_reduce_kernel(const int* __restrict__ cnt,
                                                          int* __restrict__ bsum) {
  __shared__ int s[256];
  int i = blockIdx.x * 256 + threadIdx.x;
  s[threadIdx.x] = (i < NN) ? cnt[i] : 0;
  __syncthreads();
  for (int o = 128; o > 0; o >>= 1) {
    if (threadIdx.x < o) s[threadIdx.x] += s[threadIdx.x + o];
    __syncthreads();
  }
  if (threadIdx.x == 0) bsum[blockIdx.x] = s[0];
}

__global__ __launch_bounds__(256) void scan_tops_kernel(const int* __restrict__ bsum,
                                                        int* __restrict__ boff, int nb) {
  __shared__ int s[256];
  int v = (threadIdx.x < nb) ? bsum[threadIdx.x] : 0;
  s[threadIdx.x] = v;
  __syncthreads();
  for (int o = 1; o < 256; o <<= 1) {
    int t = (threadIdx.x >= o) ? s[threadIdx.x - o] : 0;
    __syncthreads();
    s[threadIdx.x] += t;
    __syncthreads();
  }
  if (threadIdx.x < nb) boff[threadIdx.x] = s[threadIdx.x] - v;
}

__global__ __launch_bounds__(256) void scan_final_kernel(const int* __restrict__ cnt,
                                                         const int* __restrict__ boff,
                                                         int* __restrict__ rowptr,
                                                         int* __restrict__ cursor) {
  __shared__ int s[256];
  int i = blockIdx.x * 256 + threadIdx.x;
  int v = (i < NN) ? cnt[i] : 0;
  s[threadIdx.x] = v;
  __syncthreads();
  for (int o = 1; o < 256; o <<= 1) {
    int t = (threadIdx.x >= o) ? s[threadIdx.x - o] : 0;
    __syncthreads();
    s[threadIdx.x] += t;
    __syncthreads();
  }
  int ex = boff[blockIdx.x] + s[threadIdx.x] - v;
  if (i < NN) { rowptr[i] = ex; cursor[i] = ex; }
  if (i == NN - 1) rowptr[NN] = ex + v;
}

__global__ __launch_bounds__(256) void fill_kernel(const int* __restrict__ src,
                                                   const int* __restrict__ dst,
                                                   int* __restrict__ cursor,
                                                   int* __restrict__ col, int n) {
  int e = blockIdx.x * 256 + threadIdx.x;
  if (e < n) {
    int p = atomicAdd(&cursor[dst[e]], 1);
    col[p] = src[e];
  }
}

// ---------------- aggregation (bf16): y = x + segment_sum(x[src] -> dst) ----------------
// 16 lanes per node (uint4 = 8 bf16 per lane), 16 nodes per 256-thread block.
__global__ __launch_bounds__(256) void agg_y_bf16_kernel(const unsigned short* __restrict__ X,
                                                         const int* __restrict__ rowptr,
                                                         const int* __restrict__ col,
                                                         unsigned short* __restrict__ Y) {
  int node = blockIdx.x * 16 + (threadIdx.x >> 4);
  int lane = threadIdx.x & 15;
  const uint4* X4 = reinterpret_cast<const uint4*>(X);
  uint4 sv = X4[(size_t)node * 16 + lane];
  float acc[8];
  {
    unsigned int w[4] = {sv.x, sv.y, sv.z, sv.w};
#pragma unroll
    for (int q = 0; q < 4; q++) {
      acc[2 * q]     = __uint_as_float(w[q] << 16);
      acc[2 * q + 1] = __uint_as_float(w[q] & 0xffff0000u);
    }
  }
  int s = rowptr[node], e = rowptr[node + 1];
  for (int j = s; j < e; ++j) {
    int src = col[j];
    uint4 v = X4[(size_t)src * 16 + lane];
    unsigned int w[4] = {v.x, v.y, v.z, v.w};
#pragma unroll
    for (int q = 0; q < 4; q++) {
      acc[2 * q]     += __uint_as_float(w[q] << 16);
      acc[2 * q + 1] += __uint_as_float(w[q] & 0xffff0000u);
    }
  }
  uint4 o;
  unsigned int* ow = reinterpret_cast<unsigned int*>(&o);
#pragma unroll
  for (int q = 0; q < 4; q++)
    ow[q] = (unsigned int)f2bf(acc[2 * q]) | ((unsigned int)f2bf(acc[2 * q + 1]) << 16);
  reinterpret_cast<uint4*>(Y)[(size_t)node * 16 + lane] = o;
}

// ---------------- GEMM bf16 MFMA: out = act(X @ W + b), X [NN x 128], WT [128c x 128k] ----------------
// act: 0 = BN+ReLU, 1 = ReLU, 2 = LeakyReLU(0.01)
__global__ __launch_bounds__(256) void gemm_mfma_kernel(
    const unsigned short* __restrict__ X, const unsigned short* __restrict__ WT,
    const float* __restrict__ bias, const float* __restrict__ bn_g,
    const float* __restrict__ bn_b, const float* __restrict__ bn_m,
    const float* __restrict__ bn_v, unsigned short* __restrict__ out, int act) {
  int lane = threadIdx.x & 63;
  int wv = threadIdx.x >> 6;
  int l15 = lane & 15, lk = lane >> 4;
  int c0 = wv * 32;
  // B fragments: col = lane&15, k contiguous 8 at (lane>>4)*8
  short8 bfrag[2][4];
#pragma unroll
  for (int ct = 0; ct < 2; ct++)
#pragma unroll
    for (int kk = 0; kk < 4; kk++)
      bfrag[ct][kk] = *reinterpret_cast<const short8*>(
          WT + (size_t)(c0 + ct * 16 + l15) * 128 + kk * 32 + lk * 8);
  // per-column epilogue constants
  float sc[2], sh[2];
#pragma unroll
  for (int ct = 0; ct < 2; ct++) {
    int colg = c0 + ct * 16 + l15;
    if (act == 0) {
      float s = bn_g[colg] * rsqrtf(bn_v[colg] + 1e-5f);
      sc[ct] = s;
      sh[ct] = (bias[colg] - bn_m[colg]) * s + bn_b[colg];
    } else {
      sc[ct] = 1.f;
      sh[ct] = bias[colg];
    }
  }
  for (int rt = blockIdx.x; rt < NN / 16; rt += gridDim.x) {
    int row0 = rt << 4;
    const unsigned short* xp = X + (size_t)(row0 + l15) * 128 + lk * 8;
    short8 a0 = *reinterpret_cast<const short8*>(xp);
    short8 a1 = *reinterpret_cast<const short8*>(xp + 32);
    short8 a2 = *reinterpret_cast<const short8*>(xp + 64);
    short8 a3 = *reinterpret_cast<const short8*>(xp + 96);
#pragma unroll
    for (int ct = 0; ct < 2; ct++) {
      f32x4 acc = {0.f, 0.f, 0.f, 0.f};
      acc = __builtin_amdgcn_mfma_f32_16x16x32_bf16(a0, bfrag[ct][0], acc, 0, 0, 0);
      acc = __builtin_amdgcn_mfma_f32_16x16x32_bf16(a1, bfrag[ct][1], acc, 0, 0, 0);
      acc = __builtin_amdgcn_mfma_f32_16x16x32_bf16(a2, bfrag[ct][2], acc, 0, 0, 0);
      acc = __builtin_amdgcn_mfma_f32_16x16x32_bf16(a3, bfrag[ct][3], acc, 0, 0, 0);
      int colg = c0 + ct * 16 + l15;
#pragma unroll
      for (int r = 0; r < 4; r++) {
        float v = acc[r] * sc[ct] + sh[ct];
        if (act <= 1) v = fmaxf(v, 0.f);
        else          v = v > 0.f ? v : 0.01f * v;
        out[(size_t)(row0 + lk * 4 + r) * 128 + colg] = f2bf(v);
      }
    }
  }
}

// ---------------- pooling (bf16 in, fp32 z): z[batch[r]][coloff+f] += x[r][f] ----------------
__global__ __launch_bounds__(128) void pool_bf16_kernel(const unsigned short* __restrict__ X,
                                                        const int* __restrict__ batch,
                                                        float* __restrict__ z, int coloff) {
  int f = threadIdx.x;
  int r0 = blockIdx.x * 256;
  if (r0 >= NN) return;
  int rend = r0 + 256; if (rend > NN) rend = NN;
  float acc = 0.f;
  int cur = batch[r0];
  for (int r = r0; r < rend; ++r) {
    int g = batch[r];
    if (g != cur) {
      atomicAdd(&z[(size_t)cur * (2 * DD * NL) + coloff + f], acc);
      acc = 0.f; cur = g;
    }
    acc += bf2f(X[(size_t)r * 128 + f]);
  }
  atomicAdd(&z[(size_t)cur * (2 * DD * NL) + coloff + f], acc);
}

// ---------------- head: relu(z @ Wf1 + bf1) @ Wf2 + bf2 ----------------
__global__ __launch_bounds__(128) void head_kernel(const float* __restrict__ z,
                                                   const float* __restrict__ Wf1,
                                                   const float* __restrict__ bf1,
                                                   const float* __restrict__ Wf2,
                                                   const float* __restrict__ bf2,
                                                   float* __restrict__ out) {
  int g = blockIdx.x, t = threadIdx.x;
  const float* zr = z + (size_t)g * (2 * DD * NL);
  float acc = bf1[t];
  for (int j = 0; j < 2 * DD * NL; ++j) acc += zr[j] * Wf1[(size_t)j * DD + t];
  float h = fmaxf(acc, 0.f);
  __shared__ float red[128];
  red[t] = h * Wf2[t];
  __syncthreads();
  for (int s = 64; s > 0; s >>= 1) {
    if (t < s) red[t] += red[t + s];
    __syncthreads();
  }
  if (t == 0) out[g] = red[0] + bf2[0];
}

extern "C" void kernel_launch(void* const* d_in, const int* in_sizes, int n_in,
                              void* d_out, int out_size, void* d_ws, size_t ws_size,
                              hipStream_t stream) {
  const float* x1   = (const float*)d_in[0];
  const float* x2   = (const float*)d_in[1];
  const float* W1c1 = (const float*)d_in[2];
  const float* b1c1 = (const float*)d_in[3];
  const float* bng  = (const float*)d_in[4];
  const float* bnb  = (const float*)d_in[5];
  const float* bnm  = (const float*)d_in[6];
  const float* bnv  = (const float*)d_in[7];
  const float* W2c1 = (const float*)d_in[8];
  const float* b2c1 = (const float*)d_in[9];
  const float* W1c2 = (const float*)d_in[10];
  const float* b1c2 = (const float*)d_in[11];
  const float* W2c2 = (const float*)d_in[12];
  const float* b2c2 = (const float*)d_in[13];
  const float* Wf1  = (const float*)d_in[14];
  const float* bf1  = (const float*)d_in[15];
  const float* Wf2  = (const float*)d_in[16];
  const float* bf2  = (const float*)d_in[17];
  const int* edge1  = (const int*)d_in[18];
  const int* edge2  = (const int*)d_in[19];
  const int* batch1 = (const int*)d_in[20];
  const int* batch2 = (const int*)d_in[21];
  (void)ws_size; (void)n_in; (void)in_sizes; (void)out_size;

  char* ws = (char*)d_ws;
  const size_t NB16 = (size_t)NN * DD * 2;  // 12.8 MB bf16 node buffer
  unsigned short* bufX = (unsigned short*)(ws);
  unsigned short* bufY = (unsigned short*)(ws + NB16);
  unsigned short* bufH = (unsigned short*)(ws + 2 * NB16);
  size_t off = 3 * NB16;
  unsigned short* WT = (unsigned short*)(ws + off); off += (size_t)12 * 16384 * 2;
  int* rowptr = (int*)(ws + off); off += (((size_t)(NN + 1) * 4) + 255) & ~(size_t)255;
  int* cursor = (int*)(ws + off); off += (((size_t)NN * 4) + 255) & ~(size_t)255;
  int* cnt    = (int*)(ws + off); off += (((size_t)NN * 4) + 255) & ~(size_t)255;
  int* bsum   = (int*)(ws + off); off += 256 * 4;
  int* boff   = (int*)(ws + off); off += 256 * 4;
  int* col    = (int*)(ws + off); off += (size_t)NE * 4;
  float* z    = (float*)(ws + off); off += (size_t)NG * 2 * DD * NL * 4;

  const int NB_SCAN = (NN + 255) / 256;  // 196

  // weights: fp32 [k][c] -> bf16 [c][k], 12 matrices
  dim3 wtb(256);
  cvt_wt_kernel<<<dim3(4, 4, 3), wtb, 0, stream>>>(W1c1, WT + 0 * 16384);
  cvt_wt_kernel<<<dim3(4, 4, 3), wtb, 0, stream>>>(W2c1, WT + 3 * 16384);
  cvt_wt_kernel<<<dim3(4, 4, 3), wtb, 0, stream>>>(W1c2, WT + 6 * 16384);
  cvt_wt_kernel<<<dim3(4, 4, 3), wtb, 0, stream>>>(W2c2, WT + 9 * 16384);

  hipMemsetAsync(z, 0, (size_t)NG * 2 * DD * NL * 4, stream);

  for (int ch = 0; ch < 2; ++ch) {
    const int* edge   = ch == 0 ? edge1 : edge2;
    const int* batch  = ch == 0 ? batch1 : batch2;
    const float* x0   = ch == 0 ? x1 : x2;
    const unsigned short* WT1 = WT + (ch == 0 ? 0 : 6) * 16384;
    const unsigned short* WT2 = WT + (ch == 0 ? 3 : 9) * 16384;
    const float* b1   = ch == 0 ? b1c1 : b1c2;
    const float* b2   = ch == 0 ? b2c1 : b2c2;
    const int act1 = ch == 0 ? 0 : 1;  // ch1: BN+ReLU, ch2: ReLU
    const int act2 = ch == 0 ? 1 : 2;  // ch1: ReLU (leaky∘relu == relu), ch2: LeakyReLU

    cvt_bf16_kernel<<<(NN * DD / 8 + 255) / 256, 256, 0, stream>>>(x0, bufX, NN * DD / 8);

    // CSR by dst (edge list shared across the channel's 3 layers)
    hipMemsetAsync(cnt, 0, (size_t)NN * 4, stream);
    hist_kernel<<<NE / 256, 256, 0, stream>>>(edge + NE, cnt, NE);
    scan_reduce_kernel<<<NB_SCAN, 256, 0, stream>>>(cnt, bsum);
    scan_tops_kernel<<<1, 256, 0, stream>>>(bsum, boff, NB_SCAN);
    scan_final_kernel<<<NB_SCAN, 256, 0, stream>>>(cnt, boff, rowptr, cursor);
    fill_kernel<<<NE / 256, 256, 0, stream>>>(edge, edge + NE, cursor, col, NE);

    for (int i = 0; i < NL; ++i) {
      agg_y_bf16_kernel<<<NN / 16, 256, 0, stream>>>(bufX, rowptr, col, bufY);
      gemm_mfma_kernel<<<1024, 256, 0, stream>>>(
          bufY, WT1 + (size_t)i * 16384, b1 + i * DD,
          bng + i * DD, bnb + i * DD, bnm + i * DD, bnv + i * DD,
          bufH, act1);
      gemm_mfma_kernel<<<1024, 256, 0, stream>>>(
          bufH, WT2 + (size_t)i * 16384, b2 + i * DD,
          bng, bnb, bnm, bnv, bufX, act2);
      pool_bf16_kernel<<<(NN + 255) / 256, 128, 0, stream>>>(bufX, batch, z,
                                                             ch * DD * NL + i * DD);
    }
  }
  head_kernel<<<NG, 128, 0, stream>>>(z, Wf1, bf1, Wf2, bf2, (float*)d_out);
}

// Round 3
// 603.707 us; speedup vs baseline: 2.3305x; 1.7675x over previous
//
#include <hip/hip_runtime.h>

#define NN 50000
#define NE 800000
#define NG 64
#define DD 128
#define NL 3
#define ZW (2 * DD * NL)  // 768

typedef __attribute__((ext_vector_type(8))) short short8;
typedef __attribute__((ext_vector_type(4))) float f32x4;

__device__ inline unsigned short f2bf(float f) {
  unsigned int u = __float_as_uint(f);
  unsigned int r = (u + 0x7fffu + ((u >> 16) & 1u)) >> 16;
  return (unsigned short)r;
}

// ---------------- fp32 -> bf16 convert (8 elems/thread) ----------------
__global__ __launch_bounds__(256) void cvt_bf16_kernel(const float* __restrict__ in,
                                                       unsigned short* __restrict__ out, int n8) {
  int i = blockIdx.x * 256 + threadIdx.x;
  if (i >= n8) return;
  const float4* in4 = reinterpret_cast<const float4*>(in);
  float4 a = in4[2 * i], b = in4[2 * i + 1];
  uint4 o;
  o.x = (unsigned int)f2bf(a.x) | ((unsigned int)f2bf(a.y) << 16);
  o.y = (unsigned int)f2bf(a.z) | ((unsigned int)f2bf(a.w) << 16);
  o.z = (unsigned int)f2bf(b.x) | ((unsigned int)f2bf(b.y) << 16);
  o.w = (unsigned int)f2bf(b.z) | ((unsigned int)f2bf(b.w) << 16);
  reinterpret_cast<uint4*>(out)[i] = o;
}

// ---------------- W [mat][k][c] fp32 -> WT [mat][c][k] bf16 ----------------
__global__ __launch_bounds__(256) void cvt_wt_kernel(const float* __restrict__ in,
                                                     unsigned short* __restrict__ out) {
  __shared__ float tile[32][33];
  int mat = blockIdx.z;
  int k0 = blockIdx.x * 32, c0 = blockIdx.y * 32;
  int tx = threadIdx.x & 31, ty = threadIdx.x >> 5;  // 8 rows per pass
  const float* ip = in + mat * 16384;
  unsigned short* op = out + mat * 16384;
#pragma unroll
  for (int rr = 0; rr < 32; rr += 8)
    tile[ty + rr][tx] = ip[(k0 + ty + rr) * 128 + (c0 + tx)];
  __syncthreads();
#pragma unroll
  for (int rr = 0; rr < 32; rr += 8)
    op[(c0 + ty + rr) * 128 + (k0 + tx)] = f2bf(tile[tx][ty + rr]);
}

// ---------------- CSR build ----------------
__global__ __launch_bounds__(256) void hist_kernel(const int* __restrict__ dst,
                                                   int* __restrict__ counts, int n) {
  int e = blockIdx.x * 256 + threadIdx.x;
  if (e < n) atomicAdd(&counts[dst[e]], 1);
}

__global__ __launch_bounds__(256) void scan_reduce_kernel(const int* __restrict__ cnt,
                                                          int* __restrict__ bsum) {
  __shared__ int s[256];
  int i = blockIdx.x * 256 + threadIdx.x;
  s[threadIdx.x] = (i < NN) ? cnt[i] : 0;
  __syncthreads();
  for (int o = 128; o > 0; o >>= 1) {
    if (threadIdx.x < o) s[threadIdx.x] += s[threadIdx.x + o];
    __syncthreads();
  }
  if (threadIdx.x == 0) bsum[blockIdx.x] = s[0];
}

__global__ __launch_bounds__(256) void scan_tops_kernel(const int* __restrict__ bsum,
                                                        int* __restrict__ boff, int nb) {
  __shared__ int s[256];
  int v = (threadIdx.x < nb) ? bsum[threadIdx.x] : 0;
  s[threadIdx.x] = v;
  __syncthreads();
  for (int o = 1; o < 256; o <<= 1) {
    int t = (threadIdx.x >= o) ? s[threadIdx.x - o] : 0;
    __syncthreads();
    s[threadIdx.x] += t;
    __syncthreads();
  }
  if (threadIdx.x < nb) boff[threadIdx.x] = s[threadIdx.x] - v;
}

__global__ __launch_bounds__(256) void scan_final_kernel(const int* __restrict__ cnt,
                                                         const int* __restrict__ boff,
                                                         int* __restrict__ rowptr,
                                                         int* __restrict__ cursor) {
  __shared__ int s[256];
  int i = blockIdx.x * 256 + threadIdx.x;
  int v = (i < NN) ? cnt[i] : 0;
  s[threadIdx.x] = v;
  __syncthreads();
  for (int o = 1; o < 256; o <<= 1) {
    int t = (threadIdx.x >= o) ? s[threadIdx.x - o] : 0;
    __syncthreads();
    s[threadIdx.x] += t;
    __syncthreads();
  }
  int ex = boff[blockIdx.x] + s[threadIdx.x] - v;
  if (i < NN) { rowptr[i] = ex; cursor[i] = ex; }
  if (i == NN - 1) rowptr[NN] = ex + v;
}

__global__ __launch_bounds__(256) void fill_kernel(const int* __restrict__ src,
                                                   const int* __restrict__ dst,
                                                   int* __restrict__ cursor,
                                                   int* __restrict__ col, int n) {
  int e = blockIdx.x * 256 + threadIdx.x;
  if (e < n) {
    int p = atomicAdd(&cursor[dst[e]], 1);
    col[p] = src[e];
  }
}

// ---------------- aggregation (bf16): y = x + segment_sum(x[src] -> dst) ----------------
// 16 lanes per node (uint4 = 8 bf16 per lane), 16 nodes per 256-thread block.
__global__ __launch_bounds__(256) void agg_y_bf16_kernel(const unsigned short* __restrict__ X,
                                                         const int* __restrict__ rowptr,
                                                         const int* __restrict__ col,
                                                         unsigned short* __restrict__ Y) {
  int node = blockIdx.x * 16 + (threadIdx.x >> 4);
  int lane = threadIdx.x & 15;
  const uint4* X4 = reinterpret_cast<const uint4*>(X);
  float acc[8];
  {
    uint4 sv = X4[(size_t)node * 16 + lane];
    unsigned int w[4] = {sv.x, sv.y, sv.z, sv.w};
#pragma unroll
    for (int q = 0; q < 4; q++) {
      acc[2 * q]     = __uint_as_float(w[q] << 16);
      acc[2 * q + 1] = __uint_as_float(w[q] & 0xffff0000u);
    }
  }
  int s = rowptr[node], e = rowptr[node + 1];
  int j = s;
  for (; j + 4 <= e; j += 4) {
    int s0 = col[j], s1 = col[j + 1], s2 = col[j + 2], s3 = col[j + 3];
    uint4 v0 = X4[(size_t)s0 * 16 + lane];
    uint4 v1 = X4[(size_t)s1 * 16 + lane];
    uint4 v2 = X4[(size_t)s2 * 16 + lane];
    uint4 v3 = X4[(size_t)s3 * 16 + lane];
    unsigned int w0[4] = {v0.x, v0.y, v0.z, v0.w};
    unsigned int w1[4] = {v1.x, v1.y, v1.z, v1.w};
    unsigned int w2[4] = {v2.x, v2.y, v2.z, v2.w};
    unsigned int w3[4] = {v3.x, v3.y, v3.z, v3.w};
#pragma unroll
    for (int q = 0; q < 4; q++) {
      acc[2 * q]     += __uint_as_float(w0[q] << 16) + __uint_as_float(w1[q] << 16) +
                        __uint_as_float(w2[q] << 16) + __uint_as_float(w3[q] << 16);
      acc[2 * q + 1] += __uint_as_float(w0[q] & 0xffff0000u) + __uint_as_float(w1[q] & 0xffff0000u) +
                        __uint_as_float(w2[q] & 0xffff0000u) + __uint_as_float(w3[q] & 0xffff0000u);
    }
  }
  for (; j < e; ++j) {
    int src = col[j];
    uint4 v = X4[(size_t)src * 16 + lane];
    unsigned int w[4] = {v.x, v.y, v.z, v.w};
#pragma unroll
    for (int q = 0; q < 4; q++) {
      acc[2 * q]     += __uint_as_float(w[q] << 16);
      acc[2 * q + 1] += __uint_as_float(w[q] & 0xffff0000u);
    }
  }
  uint4 o;
  unsigned int* ow = reinterpret_cast<unsigned int*>(&o);
#pragma unroll
  for (int q = 0; q < 4; q++)
    ow[q] = (unsigned int)f2bf(acc[2 * q]) | ((unsigned int)f2bf(acc[2 * q + 1]) << 16);
  reinterpret_cast<uint4*>(Y)[(size_t)node * 16 + lane] = o;
}

// ---------------- GEMM bf16 MFMA (+optional fused global_add_pool) ----------------
// out = act(X @ W + b); if batch!=nullptr also z[batch[row]][coloff+col] += out (fp32, pre-round)
// act: 0 = BN+ReLU, 1 = ReLU, 2 = LeakyReLU(0.01)
__global__ __launch_bounds__(256) void gemm_mfma_kernel(
    const unsigned short* __restrict__ X, const unsigned short* __restrict__ WT,
    const float* __restrict__ bias, const float* __restrict__ bn_g,
    const float* __restrict__ bn_b, const float* __restrict__ bn_m,
    const float* __restrict__ bn_v, unsigned short* __restrict__ out, int act,
    const int* __restrict__ batch, float* __restrict__ z, int coloff) {
  int lane = threadIdx.x & 63;
  int wv = threadIdx.x >> 6;
  int l15 = lane & 15, lk = lane >> 4;
  int c0 = wv * 32;
  // B fragments: col = lane&15, k contiguous 8 at (lane>>4)*8
  short8 bfrag[2][4];
#pragma unroll
  for (int ct = 0; ct < 2; ct++)
#pragma unroll
    for (int kk = 0; kk < 4; kk++)
      bfrag[ct][kk] = *reinterpret_cast<const short8*>(
          WT + (size_t)(c0 + ct * 16 + l15) * 128 + kk * 32 + lk * 8);
  // per-column epilogue constants
  float sc[2], sh[2];
#pragma unroll
  for (int ct = 0; ct < 2; ct++) {
    int colg = c0 + ct * 16 + l15;
    if (act == 0) {
      float s = bn_g[colg] * rsqrtf(bn_v[colg] + 1e-5f);
      sc[ct] = s;
      sh[ct] = (bias[colg] - bn_m[colg]) * s + bn_b[colg];
    } else {
      sc[ct] = 1.f;
      sh[ct] = bias[colg];
    }
  }
  for (int rt = blockIdx.x; rt < NN / 16; rt += gridDim.x) {
    int row0 = rt << 4;
    const unsigned short* xp = X + (size_t)(row0 + l15) * 128 + lk * 8;
    short8 a0 = *reinterpret_cast<const short8*>(xp);
    short8 a1 = *reinterpret_cast<const short8*>(xp + 32);
    short8 a2 = *reinterpret_cast<const short8*>(xp + 64);
    short8 a3 = *reinterpret_cast<const short8*>(xp + 96);
#pragma unroll
    for (int ct = 0; ct < 2; ct++) {
      f32x4 acc = {0.f, 0.f, 0.f, 0.f};
      acc = __builtin_amdgcn_mfma_f32_16x16x32_bf16(a0, bfrag[ct][0], acc, 0, 0, 0);
      acc = __builtin_amdgcn_mfma_f32_16x16x32_bf16(a1, bfrag[ct][1], acc, 0, 0, 0);
      acc = __builtin_amdgcn_mfma_f32_16x16x32_bf16(a2, bfrag[ct][2], acc, 0, 0, 0);
      acc = __builtin_amdgcn_mfma_f32_16x16x32_bf16(a3, bfrag[ct][3], acc, 0, 0, 0);
      int colg = c0 + ct * 16 + l15;
      float v[4];
#pragma unroll
      for (int r = 0; r < 4; r++) {
        float t = acc[r] * sc[ct] + sh[ct];
        if (act <= 1) t = fmaxf(t, 0.f);
        else          t = t > 0.f ? t : 0.01f * t;
        v[r] = t;
        out[(size_t)(row0 + lk * 4 + r) * 128 + colg] = f2bf(t);
      }
      if (batch) {
        int g0 = batch[row0], g15 = batch[row0 + 15];
        if (g0 == g15) {
          float s = v[0] + v[1] + v[2] + v[3];
          s += __shfl_xor(s, 16);
          s += __shfl_xor(s, 32);
          if (lk == 0) atomicAdd(&z[(size_t)g0 * ZW + coloff + colg], s);
        } else {
#pragma unroll
          for (int r = 0; r < 4; r++)
            atomicAdd(&z[(size_t)batch[row0 + lk * 4 + r] * ZW + coloff + colg], v[r]);
        }
      }
    }
  }
}

// ---------------- head: relu(z @ Wf1 + bf1) @ Wf2 + bf2 ----------------
__global__ __launch_bounds__(128) void head_kernel(const float* __restrict__ z,
                                                   const float* __restrict__ Wf1,
                                                   const float* __restrict__ bf1,
                                                   const float* __restrict__ Wf2,
                                                   const float* __restrict__ bf2,
                                                   float* __restrict__ out) {
  int g = blockIdx.x, t = threadIdx.x;
  const float* zr = z + (size_t)g * ZW;
  float acc = bf1[t];
  for (int j = 0; j < ZW; ++j) acc += zr[j] * Wf1[(size_t)j * DD + t];
  float h = fmaxf(acc, 0.f);
  __shared__ float red[128];
  red[t] = h * Wf2[t];
  __syncthreads();
  for (int s = 64; s > 0; s >>= 1) {
    if (t < s) red[t] += red[t + s];
    __syncthreads();
  }
  if (t == 0) out[g] = red[0] + bf2[0];
}

extern "C" void kernel_launch(void* const* d_in, const int* in_sizes, int n_in,
                              void* d_out, int out_size, void* d_ws, size_t ws_size,
                              hipStream_t stream) {
  const float* x1   = (const float*)d_in[0];
  const float* x2   = (const float*)d_in[1];
  const float* W1c1 = (const float*)d_in[2];
  const float* b1c1 = (const float*)d_in[3];
  const float* bng  = (const float*)d_in[4];
  const float* bnb  = (const float*)d_in[5];
  const float* bnm  = (const float*)d_in[6];
  const float* bnv  = (const float*)d_in[7];
  const float* W2c1 = (const float*)d_in[8];
  const float* b2c1 = (const float*)d_in[9];
  const float* W1c2 = (const float*)d_in[10];
  const float* b1c2 = (const float*)d_in[11];
  const float* W2c2 = (const float*)d_in[12];
  const float* b2c2 = (const float*)d_in[13];
  const float* Wf1  = (const float*)d_in[14];
  const float* bf1  = (const float*)d_in[15];
  const float* Wf2  = (const float*)d_in[16];
  const float* bf2  = (const float*)d_in[17];
  const int* edge1  = (const int*)d_in[18];
  const int* edge2  = (const int*)d_in[19];
  const int* batch1 = (const int*)d_in[20];
  const int* batch2 = (const int*)d_in[21];
  (void)ws_size; (void)n_in; (void)in_sizes; (void)out_size;

  char* ws = (char*)d_ws;
  const size_t NB16 = (size_t)NN * DD * 2;  // 12.8 MB bf16 node buffer
  unsigned short* bufX = (unsigned short*)(ws);
  unsigned short* bufY = (unsigned short*)(ws + NB16);
  unsigned short* bufH = (unsigned short*)(ws + 2 * NB16);
  size_t off = 3 * NB16;
  unsigned short* WT = (unsigned short*)(ws + off); off += (size_t)12 * 16384 * 2;
  int* rowptr = (int*)(ws + off); off += (((size_t)(NN + 1) * 4) + 255) & ~(size_t)255;
  int* cursor = (int*)(ws + off); off += (((size_t)NN * 4) + 255) & ~(size_t)255;
  int* cnt    = (int*)(ws + off); off += (((size_t)NN * 4) + 255) & ~(size_t)255;
  int* bsum   = (int*)(ws + off); off += 256 * 4;
  int* boff   = (int*)(ws + off); off += 256 * 4;
  int* col    = (int*)(ws + off); off += (size_t)NE * 4;
  float* z    = (float*)(ws + off); off += (size_t)NG * ZW * 4;

  const int NB_SCAN = (NN + 255) / 256;  // 196

  // weights: fp32 [k][c] -> bf16 [c][k], 12 matrices
  dim3 wtb(256);
  cvt_wt_kernel<<<dim3(4, 4, 3), wtb, 0, stream>>>(W1c1, WT + 0 * 16384);
  cvt_wt_kernel<<<dim3(4, 4, 3), wtb, 0, stream>>>(W2c1, WT + 3 * 16384);
  cvt_wt_kernel<<<dim3(4, 4, 3), wtb, 0, stream>>>(W1c2, WT + 6 * 16384);
  cvt_wt_kernel<<<dim3(4, 4, 3), wtb, 0, stream>>>(W2c2, WT + 9 * 16384);

  hipMemsetAsync(z, 0, (size_t)NG * ZW * 4, stream);

  for (int ch = 0; ch < 2; ++ch) {
    const int* edge   = ch == 0 ? edge1 : edge2;
    const int* batch  = ch == 0 ? batch1 : batch2;
    const float* x0   = ch == 0 ? x1 : x2;
    const unsigned short* WT1 = WT + (ch == 0 ? 0 : 6) * 16384;
    const unsigned short* WT2 = WT + (ch == 0 ? 3 : 9) * 16384;
    const float* b1   = ch == 0 ? b1c1 : b1c2;
    const float* b2   = ch == 0 ? b2c1 : b2c2;
    const int act1 = ch == 0 ? 0 : 1;  // ch1: BN+ReLU, ch2: ReLU
    const int act2 = ch == 0 ? 1 : 2;  // ch1: ReLU (leaky∘relu == relu), ch2: LeakyReLU

    cvt_bf16_kernel<<<(NN * DD / 8 + 255) / 256, 256, 0, stream>>>(x0, bufX, NN * DD / 8);

    // CSR by dst (edge list shared across the channel's 3 layers)
    hipMemsetAsync(cnt, 0, (size_t)NN * 4, stream);
    hist_kernel<<<NE / 256, 256, 0, stream>>>(edge + NE, cnt, NE);
    scan_reduce_kernel<<<NB_SCAN, 256, 0, stream>>>(cnt, bsum);
    scan_tops_kernel<<<1, 256, 0, stream>>>(bsum, boff, NB_SCAN);
    scan_final_kernel<<<NB_SCAN, 256, 0, stream>>>(cnt, boff, rowptr, cursor);
    fill_kernel<<<NE / 256, 256, 0, stream>>>(edge, edge + NE, cursor, col, NE);

    for (int i = 0; i < NL; ++i) {
      agg_y_bf16_kernel<<<NN / 16, 256, 0, stream>>>(bufX, rowptr, col, bufY);
      gemm_mfma_kernel<<<1024, 256, 0, stream>>>(
          bufY, WT1 + (size_t)i * 16384, b1 + i * DD,
          bng + i * DD, bnb + i * DD, bnm + i * DD, bnv + i * DD,
          bufH, act1, nullptr, nullptr, 0);
      gemm_mfma_kernel<<<1024, 256, 0, stream>>>(
          bufH, WT2 + (size_t)i * 16384, b2 + i * DD,
          bng, bnb, bnm, bnv, bufX, act2,
          batch, z, ch * DD * NL + i * DD);
    }
  }
  head_kernel<<<NG, 128, 0, stream>>>(z, Wf1, bf1, Wf2, bf2, (float*)d_out);
}

// Round 4
// 512.404 us; speedup vs baseline: 2.7458x; 1.1782x over previous
//
#include <hip/hip_runtime.h>

#define NN 50000
#define NE 800000
#define NG 64
#define DD 128
#define NL 3
#define ZW (2 * DD * NL)  // 768
#define NBUCK 8
#define BUCK_DIV 6250     // nodes per bucket
#define CAP 106496        // pair capacity per (ch,bucket)
#define NSLICE 64         // slices per group for affine kernels
#define BPC 782           // bucket_kernel blocks per channel (1024 edges each)

typedef __attribute__((ext_vector_type(8))) short short8;
typedef __attribute__((ext_vector_type(4))) float f32x4;

__device__ inline unsigned short f2bf(float f) {
  unsigned int u = __float_as_uint(f);
  unsigned int r = (u + 0x7fffu + ((u >> 16) & 1u)) >> 16;
  return (unsigned short)r;
}

// ---------------- fp32 -> bf16 convert (8 elems/thread) ----------------
__global__ __launch_bounds__(256) void cvt_bf16_kernel(const float* __restrict__ in,
                                                       unsigned short* __restrict__ out, int n8) {
  int i = blockIdx.x * 256 + threadIdx.x;
  if (i >= n8) return;
  const float4* in4 = reinterpret_cast<const float4*>(in);
  float4 a = in4[2 * i], b = in4[2 * i + 1];
  uint4 o;
  o.x = (unsigned int)f2bf(a.x) | ((unsigned int)f2bf(a.y) << 16);
  o.y = (unsigned int)f2bf(a.z) | ((unsigned int)f2bf(a.w) << 16);
  o.z = (unsigned int)f2bf(b.x) | ((unsigned int)f2bf(b.y) << 16);
  o.w = (unsigned int)f2bf(b.z) | ((unsigned int)f2bf(b.w) << 16);
  reinterpret_cast<uint4*>(out)[i] = o;
}

// ---------------- W [mat][k][c] fp32 -> WT [mat][c][k] bf16 ----------------
__global__ __launch_bounds__(256) void cvt_wt_kernel(const float* __restrict__ in,
                                                     unsigned short* __restrict__ out) {
  __shared__ float tile[32][33];
  int mat = blockIdx.z;
  int k0 = blockIdx.x * 32, c0 = blockIdx.y * 32;
  int tx = threadIdx.x & 31, ty = threadIdx.x >> 5;
  const float* ip = in + mat * 16384;
  unsigned short* op = out + mat * 16384;
#pragma unroll
  for (int rr = 0; rr < 32; rr += 8)
    tile[ty + rr][tx] = ip[(k0 + ty + rr) * 128 + (c0 + tx)];
  __syncthreads();
#pragma unroll
  for (int rr = 0; rr < 32; rr += 8)
    op[(c0 + ty + rr) * 128 + (k0 + tx)] = f2bf(tile[tx][ty + rr]);
}

// ---------------- pass 1: bucket edges by dst range (both channels) ----------------
__global__ __launch_bounds__(256) void bucket_kernel(const int* __restrict__ e1,
                                                     const int* __restrict__ e2,
                                                     int* __restrict__ bcur,
                                                     uint2* __restrict__ pairs) {
  int ch = blockIdx.x >= BPC;
  int blk = blockIdx.x - ch * BPC;
  const int* E = ch ? e2 : e1;
  int base = blk * 1024;
  __shared__ int lcnt[NBUCK], gbase[NBUCK];
  if (threadIdx.x < NBUCK) lcnt[threadIdx.x] = 0;
  __syncthreads();
  int g[4], l[4], src[4], dst[4];
#pragma unroll
  for (int k = 0; k < 4; k++) {
    int e = base + k * 256 + threadIdx.x;
    if (e < NE) {
      src[k] = E[e]; dst[k] = E[NE + e];
      g[k] = dst[k] / BUCK_DIV;
      l[k] = atomicAdd(&lcnt[g[k]], 1);
    } else g[k] = -1;
  }
  __syncthreads();
  if (threadIdx.x < NBUCK)
    gbase[threadIdx.x] = atomicAdd(&bcur[ch * NBUCK + threadIdx.x], lcnt[threadIdx.x]);
  __syncthreads();
#pragma unroll
  for (int k = 0; k < 4; k++)
    if (g[k] >= 0)
      pairs[(size_t)(ch * NBUCK + g[k]) * CAP + gbase[g[k]] + l[k]] =
          make_uint2((unsigned)src[k], (unsigned)dst[k]);
}

// ---------------- XCD-affine histogram over bucketed pairs ----------------
__global__ __launch_bounds__(256) void hist_affine_kernel(const uint2* __restrict__ pairs,
                                                          const int* __restrict__ bcur,
                                                          int* __restrict__ cnt) {
  int g = blockIdx.x & 15;       // ch*8 + bucket; XCD = bid%8 = g%8 (heuristic)
  int slice = blockIdx.x >> 4;
  int ch = g >> 3;
  int count = bcur[g];
  const uint2* p = pairs + (size_t)g * CAP;
  int per = (count + NSLICE - 1) / NSLICE;
  int s0 = slice * per, s1 = min(s0 + per, count);
  for (int e = s0 + threadIdx.x; e < s1; e += 256)
    atomicAdd(&cnt[ch * NN + (int)p[e].y], 1);
}

// ---------------- scans (both channels; 196 blocks/channel) ----------------
__global__ __launch_bounds__(256) void scan_reduce_kernel(const int* __restrict__ cnt,
                                                          int* __restrict__ bsum) {
  __shared__ int s[256];
  int ch = blockIdx.x >= 196;
  int blk = blockIdx.x - ch * 196;
  int i = blk * 256 + threadIdx.x;
  s[threadIdx.x] = (i < NN) ? cnt[ch * NN + i] : 0;
  __syncthreads();
  for (int o = 128; o > 0; o >>= 1) {
    if (threadIdx.x < o) s[threadIdx.x] += s[threadIdx.x + o];
    __syncthreads();
  }
  if (threadIdx.x == 0) bsum[blockIdx.x] = s[0];
}

__global__ __launch_bounds__(256) void scan_tops_kernel(const int* __restrict__ bsum,
                                                        int* __restrict__ boff) {
  __shared__ int s[256];
  int ch = blockIdx.x;
  int v = (threadIdx.x < 196) ? bsum[ch * 196 + threadIdx.x] : 0;
  s[threadIdx.x] = v;
  __syncthreads();
  for (int o = 1; o < 256; o <<= 1) {
    int t = (threadIdx.x >= o) ? s[threadIdx.x - o] : 0;
    __syncthreads();
    s[threadIdx.x] += t;
    __syncthreads();
  }
  if (threadIdx.x < 196) boff[ch * 196 + threadIdx.x] = s[threadIdx.x] - v;
}

__global__ __launch_bounds__(256) void scan_final_kernel(const int* __restrict__ cnt,
                                                         const int* __restrict__ boff,
                                                         int* __restrict__ rowptr,
                                                         int* __restrict__ cursor) {
  __shared__ int s[256];
  int ch = blockIdx.x >= 196;
  int blk = blockIdx.x - ch * 196;
  int i = blk * 256 + threadIdx.x;
  int v = (i < NN) ? cnt[ch * NN + i] : 0;
  s[threadIdx.x] = v;
  __syncthreads();
  for (int o = 1; o < 256; o <<= 1) {
    int t = (threadIdx.x >= o) ? s[threadIdx.x - o] : 0;
    __syncthreads();
    s[threadIdx.x] += t;
    __syncthreads();
  }
  int ex = boff[ch * 196 + blk] + s[threadIdx.x] - v;
  if (i < NN) { rowptr[ch * (NN + 1) + i] = ex; cursor[ch * NN + i] = ex; }
  if (i == NN - 1) rowptr[ch * (NN + 1) + NN] = ex + v;
}

// ---------------- XCD-affine CSR fill from bucketed pairs ----------------
__global__ __launch_bounds__(256) void fill_affine_kernel(const uint2* __restrict__ pairs,
                                                          const int* __restrict__ bcur,
                                                          int* __restrict__ cursor,
                                                          int* __restrict__ col) {
  int g = blockIdx.x & 15;
  int slice = blockIdx.x >> 4;
  int ch = g >> 3;
  int count = bcur[g];
  const uint2* p = pairs + (size_t)g * CAP;
  int per = (count + NSLICE - 1) / NSLICE;
  int s0 = slice * per, s1 = min(s0 + per, count);
  for (int e = s0 + threadIdx.x; e < s1; e += 256) {
    uint2 pr = p[e];
    int pos = atomicAdd(&cursor[ch * NN + (int)pr.y], 1);
    col[ch * NE + pos] = (int)pr.x;
  }
}

// ---------------- aggregation (combined 100k nodes): y = x + sum_{src->dst} x[src] ----------------
__global__ __launch_bounds__(256) void agg_kernel(const unsigned short* __restrict__ X,
                                                  const int* __restrict__ rowptr,
                                                  const int* __restrict__ col,
                                                  unsigned short* __restrict__ Y) {
  int node = blockIdx.x * 16 + (threadIdx.x >> 4);  // 0..99999
  int lane = threadIdx.x & 15;
  int ch = node >= NN;
  int nl = node - ch * NN;
  const int* rp = rowptr + ch * (NN + 1);
  const int* cl = col + ch * NE;
  const uint4* X4 = reinterpret_cast<const uint4*>(X);
  size_t chbase = (size_t)ch * NN * 16;
  float acc[8];
  {
    uint4 sv = X4[(size_t)node * 16 + lane];
    unsigned int w[4] = {sv.x, sv.y, sv.z, sv.w};
#pragma unroll
    for (int q = 0; q < 4; q++) {
      acc[2 * q]     = __uint_as_float(w[q] << 16);
      acc[2 * q + 1] = __uint_as_float(w[q] & 0xffff0000u);
    }
  }
  int s = rp[nl], e = rp[nl + 1];
  int j = s;
  for (; j + 8 <= e; j += 8) {
    uint4 v[8];
#pragma unroll
    for (int q = 0; q < 8; q++)
      v[q] = X4[chbase + (size_t)cl[j + q] * 16 + lane];
#pragma unroll
    for (int q = 0; q < 8; q++) {
      unsigned int w[4] = {v[q].x, v[q].y, v[q].z, v[q].w};
#pragma unroll
      for (int t = 0; t < 4; t++) {
        acc[2 * t]     += __uint_as_float(w[t] << 16);
        acc[2 * t + 1] += __uint_as_float(w[t] & 0xffff0000u);
      }
    }
  }
  for (; j < e; ++j) {
    uint4 v = X4[chbase + (size_t)cl[j] * 16 + lane];
    unsigned int w[4] = {v.x, v.y, v.z, v.w};
#pragma unroll
    for (int t = 0; t < 4; t++) {
      acc[2 * t]     += __uint_as_float(w[t] << 16);
      acc[2 * t + 1] += __uint_as_float(w[t] & 0xffff0000u);
    }
  }
  uint4 o;
  unsigned int* ow = reinterpret_cast<unsigned int*>(&o);
#pragma unroll
  for (int q = 0; q < 4; q++)
    ow[q] = (unsigned int)f2bf(acc[2 * q]) | ((unsigned int)f2bf(acc[2 * q + 1]) << 16);
  reinterpret_cast<uint4*>(Y)[(size_t)node * 16 + lane] = o;
}

// ---------------- fused layer: out = act2(act1(Y@W1+b1)@W2+b2), + pool into z ----------------
// ch0: act1 = BN+ReLU, act2 = ReLU;  ch1: act1 = ReLU, act2 = LeakyReLU(0.01)
__global__ __launch_bounds__(256) void gemm_fused_kernel(
    const unsigned short* __restrict__ Y, unsigned short* __restrict__ X,
    const unsigned short* __restrict__ WT,
    const float* __restrict__ b1c1, const float* __restrict__ b1c2,
    const float* __restrict__ b2c1, const float* __restrict__ b2c2,
    const float* __restrict__ bng, const float* __restrict__ bnb,
    const float* __restrict__ bnm, const float* __restrict__ bnv,
    const int* __restrict__ batch1, const int* __restrict__ batch2,
    float* __restrict__ z, int layer) {
  __shared__ unsigned short hlds[16][136];  // padded: +8 shorts breaks bank conflicts
  int ch = blockIdx.x >= 1024;
  int lane = threadIdx.x & 63, wv = threadIdx.x >> 6;
  int l15 = lane & 15, lk = lane >> 4;
  int c0 = wv * 32;
  const unsigned short* W1 = WT + (size_t)(ch * 6 + layer) * 16384;
  const unsigned short* W2 = WT + (size_t)(ch * 6 + 3 + layer) * 16384;
  short8 w1f[2][4], w2f[2][4];
#pragma unroll
  for (int ct = 0; ct < 2; ct++)
#pragma unroll
    for (int kk = 0; kk < 4; kk++) {
      size_t boff = (size_t)(c0 + ct * 16 + l15) * 128 + kk * 32 + lk * 8;
      w1f[ct][kk] = *reinterpret_cast<const short8*>(W1 + boff);
      w2f[ct][kk] = *reinterpret_cast<const short8*>(W2 + boff);
    }
  const float* b1 = (ch ? b1c2 : b1c1) + layer * DD;
  const float* b2 = (ch ? b2c2 : b2c1) + layer * DD;
  const int* batch = ch ? batch2 : batch1;
  float sc1[2], sh1[2], sh2[2];
#pragma unroll
  for (int ct = 0; ct < 2; ct++) {
    int colg = c0 + ct * 16 + l15;
    if (!ch) {
      float s = bng[layer * DD + colg] * rsqrtf(bnv[layer * DD + colg] + 1e-5f);
      sc1[ct] = s;
      sh1[ct] = (b1[colg] - bnm[layer * DD + colg]) * s + bnb[layer * DD + colg];
    } else {
      sc1[ct] = 1.f;
      sh1[ct] = b1[colg];
    }
    sh2[ct] = b2[colg];
  }
  for (int t = (ch ? blockIdx.x - 1024 : blockIdx.x); t < 3125; t += 1024) {
    int r0l = t * 16;
    size_t r0g = (size_t)ch * NN + r0l;
    const unsigned short* yp = Y + (r0g + l15) * 128 + lk * 8;
    short8 a0 = *reinterpret_cast<const short8*>(yp);
    short8 a1 = *reinterpret_cast<const short8*>(yp + 32);
    short8 a2 = *reinterpret_cast<const short8*>(yp + 64);
    short8 a3 = *reinterpret_cast<const short8*>(yp + 96);
#pragma unroll
    for (int ct = 0; ct < 2; ct++) {
      f32x4 acc = {0.f, 0.f, 0.f, 0.f};
      acc = __builtin_amdgcn_mfma_f32_16x16x32_bf16(a0, w1f[ct][0], acc, 0, 0, 0);
      acc = __builtin_amdgcn_mfma_f32_16x16x32_bf16(a1, w1f[ct][1], acc, 0, 0, 0);
      acc = __builtin_amdgcn_mfma_f32_16x16x32_bf16(a2, w1f[ct][2], acc, 0, 0, 0);
      acc = __builtin_amdgcn_mfma_f32_16x16x32_bf16(a3, w1f[ct][3], acc, 0, 0, 0);
      int colg = c0 + ct * 16 + l15;
#pragma unroll
      for (int r = 0; r < 4; r++) {
        float tv = fmaxf(acc[r] * sc1[ct] + sh1[ct], 0.f);
        hlds[lk * 4 + r][colg] = f2bf(tv);
      }
    }
    __syncthreads();
    short8 h0 = *reinterpret_cast<const short8*>(&hlds[l15][lk * 8]);
    short8 h1 = *reinterpret_cast<const short8*>(&hlds[l15][32 + lk * 8]);
    short8 h2 = *reinterpret_cast<const short8*>(&hlds[l15][64 + lk * 8]);
    short8 h3 = *reinterpret_cast<const short8*>(&hlds[l15][96 + lk * 8]);
#pragma unroll
    for (int ct = 0; ct < 2; ct++) {
      f32x4 acc = {0.f, 0.f, 0.f, 0.f};
      acc = __builtin_amdgcn_mfma_f32_16x16x32_bf16(h0, w2f[ct][0], acc, 0, 0, 0);
      acc = __builtin_amdgcn_mfma_f32_16x16x32_bf16(h1, w2f[ct][1], acc, 0, 0, 0);
      acc = __builtin_amdgcn_mfma_f32_16x16x32_bf16(h2, w2f[ct][2], acc, 0, 0, 0);
      acc = __builtin_amdgcn_mfma_f32_16x16x32_bf16(h3, w2f[ct][3], acc, 0, 0, 0);
      int colg = c0 + ct * 16 + l15;
      float v[4];
#pragma unroll
      for (int r = 0; r < 4; r++) {
        float tv = acc[r] + sh2[ct];
        if (!ch) tv = fmaxf(tv, 0.f);
        else     tv = tv > 0.f ? tv : 0.01f * tv;
        v[r] = tv;
        X[(r0g + lk * 4 + r) * 128 + colg] = f2bf(tv);
      }
      int zc = ch * (DD * NL) + layer * DD + colg;
      int g0 = batch[r0l], g15 = batch[r0l + 15];
      if (g0 == g15) {
        float s = v[0] + v[1] + v[2] + v[3];
        s += __shfl_xor(s, 16);
        s += __shfl_xor(s, 32);
        if (lk == 0) atomicAdd(&z[(size_t)g0 * ZW + zc], s);
      } else {
#pragma unroll
        for (int r = 0; r < 4; r++)
          atomicAdd(&z[(size_t)batch[r0l + lk * 4 + r] * ZW + zc], v[r]);
      }
    }
    __syncthreads();
  }
}

// ---------------- head: relu(z @ Wf1 + bf1) @ Wf2 + bf2 ----------------
__global__ __launch_bounds__(128) void head_kernel(const float* __restrict__ z,
                                                   const float* __restrict__ Wf1,
                                                   const float* __restrict__ bf1,
                                                   const float* __restrict__ Wf2,
                                                   const float* __restrict__ bf2,
                                                   float* __restrict__ out) {
  int g = blockIdx.x, t = threadIdx.x;
  const float* zr = z + (size_t)g * ZW;
  float acc = bf1[t];
  for (int j = 0; j < ZW; ++j) acc += zr[j] * Wf1[(size_t)j * DD + t];
  float h = fmaxf(acc, 0.f);
  __shared__ float red[128];
  red[t] = h * Wf2[t];
  __syncthreads();
  for (int s = 64; s > 0; s >>= 1) {
    if (t < s) red[t] += red[t + s];
    __syncthreads();
  }
  if (t == 0) out[g] = red[0] + bf2[0];
}

extern "C" void kernel_launch(void* const* d_in, const int* in_sizes, int n_in,
                              void* d_out, int out_size, void* d_ws, size_t ws_size,
                              hipStream_t stream) {
  const float* x1   = (const float*)d_in[0];
  const float* x2   = (const float*)d_in[1];
  const float* W1c1 = (const float*)d_in[2];
  const float* b1c1 = (const float*)d_in[3];
  const float* bng  = (const float*)d_in[4];
  const float* bnb  = (const float*)d_in[5];
  const float* bnm  = (const float*)d_in[6];
  const float* bnv  = (const float*)d_in[7];
  const float* W2c1 = (const float*)d_in[8];
  const float* b2c1 = (const float*)d_in[9];
  const float* W1c2 = (const float*)d_in[10];
  const float* b1c2 = (const float*)d_in[11];
  const float* W2c2 = (const float*)d_in[12];
  const float* b2c2 = (const float*)d_in[13];
  const float* Wf1  = (const float*)d_in[14];
  const float* bf1  = (const float*)d_in[15];
  const float* Wf2  = (const float*)d_in[16];
  const float* bf2  = (const float*)d_in[17];
  const int* edge1  = (const int*)d_in[18];
  const int* edge2  = (const int*)d_in[19];
  const int* batch1 = (const int*)d_in[20];
  const int* batch2 = (const int*)d_in[21];
  (void)ws_size; (void)n_in; (void)in_sizes; (void)out_size;

  char* ws = (char*)d_ws;
  const size_t NB16 = (size_t)2 * NN * DD * 2;  // 25.6 MB combined node buffer
  unsigned short* bufX = (unsigned short*)(ws);
  unsigned short* bufY = (unsigned short*)(ws + NB16);
  size_t off = 2 * NB16;
  unsigned short* WT = (unsigned short*)(ws + off); off += (size_t)12 * 16384 * 2;
  uint2* pairs = (uint2*)(ws + off); off += (size_t)16 * CAP * 8;
  int* col    = (int*)(ws + off); off += (size_t)2 * NE * 4;
  int* rowptr = (int*)(ws + off); off += (((size_t)2 * (NN + 1) * 4) + 255) & ~(size_t)255;
  int* cursor = (int*)(ws + off); off += (((size_t)2 * NN * 4) + 255) & ~(size_t)255;
  int* cnt    = (int*)(ws + off); off += (((size_t)2 * NN * 4) + 255) & ~(size_t)255;
  int* bsum   = (int*)(ws + off); off += 512 * 4;
  int* boff   = (int*)(ws + off); off += 512 * 4;
  int* bcur   = (int*)(ws + off); off += 256;
  float* z    = (float*)(ws + off); off += (size_t)NG * ZW * 4;

  // weights: fp32 [k][c] -> bf16 [c][k], 12 matrices
  cvt_wt_kernel<<<dim3(4, 4, 3), 256, 0, stream>>>(W1c1, WT + 0 * 16384);
  cvt_wt_kernel<<<dim3(4, 4, 3), 256, 0, stream>>>(W2c1, WT + 3 * 16384);
  cvt_wt_kernel<<<dim3(4, 4, 3), 256, 0, stream>>>(W1c2, WT + 6 * 16384);
  cvt_wt_kernel<<<dim3(4, 4, 3), 256, 0, stream>>>(W2c2, WT + 9 * 16384);

  hipMemsetAsync(z, 0, (size_t)NG * ZW * 4, stream);
  hipMemsetAsync(cnt, 0, (size_t)2 * NN * 4, stream);
  hipMemsetAsync(bcur, 0, 64, stream);

  cvt_bf16_kernel<<<(NN * DD / 8 + 255) / 256, 256, 0, stream>>>(x1, bufX, NN * DD / 8);
  cvt_bf16_kernel<<<(NN * DD / 8 + 255) / 256, 256, 0, stream>>>(x2, bufX + (size_t)NN * DD,
                                                                 NN * DD / 8);

  // CSR build (both channels)
  bucket_kernel<<<2 * BPC, 256, 0, stream>>>(edge1, edge2, bcur, pairs);
  hist_affine_kernel<<<16 * NSLICE, 256, 0, stream>>>(pairs, bcur, cnt);
  scan_reduce_kernel<<<392, 256, 0, stream>>>(cnt, bsum);
  scan_tops_kernel<<<2, 256, 0, stream>>>(bsum, boff);
  scan_final_kernel<<<392, 256, 0, stream>>>(cnt, boff, rowptr, cursor);
  fill_affine_kernel<<<16 * NSLICE, 256, 0, stream>>>(pairs, bcur, cursor, col);

  for (int i = 0; i < NL; ++i) {
    agg_kernel<<<2 * NN / 16, 256, 0, stream>>>(bufX, rowptr, col, bufY);
    gemm_fused_kernel<<<2048, 256, 0, stream>>>(bufY, bufX, WT,
                                                b1c1, b1c2, b2c1, b2c2,
                                                bng, bnb, bnm, bnv,
                                                batch1, batch2, z, i);
  }
  head_kernel<<<NG, 128, 0, stream>>>(z, Wf1, bf1, Wf2, bf2, (float*)d_out);
}

// Round 5
// 394.385 us; speedup vs baseline: 3.5674x; 1.2992x over previous
//
#include <hip/hip_runtime.h>

#define NN 50000
#define NE 800000
#define NG 64
#define DD 128
#define NL 3
#define ZW (2 * DD * NL)  // 768
#define NB2 128           // sub-buckets per channel
#define NPB 391           // nodes per bucket (ceil(NN/NB2))
#define CAP2 8192         // pair capacity per bucket (mean 6250, sd ~79)
#define CHUNK 4096        // edges per pass-1 block
#define P1B 196           // pass-1 blocks per channel

typedef __attribute__((ext_vector_type(8))) short short8;
typedef __attribute__((ext_vector_type(4))) float f32x4;

__device__ inline unsigned short f2bf(float f) {
  unsigned int u = __float_as_uint(f);
  unsigned int r = (u + 0x7fffu + ((u >> 16) & 1u)) >> 16;
  return (unsigned short)r;
}

// ---------------- fp32 -> bf16 convert (8 elems/thread) ----------------
__global__ __launch_bounds__(256) void cvt_bf16_kernel(const float* __restrict__ in,
                                                       unsigned short* __restrict__ out, int n8) {
  int i = blockIdx.x * 256 + threadIdx.x;
  if (i >= n8) return;
  const float4* in4 = reinterpret_cast<const float4*>(in);
  float4 a = in4[2 * i], b = in4[2 * i + 1];
  uint4 o;
  o.x = (unsigned int)f2bf(a.x) | ((unsigned int)f2bf(a.y) << 16);
  o.y = (unsigned int)f2bf(a.z) | ((unsigned int)f2bf(a.w) << 16);
  o.z = (unsigned int)f2bf(b.x) | ((unsigned int)f2bf(b.y) << 16);
  o.w = (unsigned int)f2bf(b.z) | ((unsigned int)f2bf(b.w) << 16);
  reinterpret_cast<uint4*>(out)[i] = o;
}

// ---------------- W [mat][k][c] fp32 -> WT [mat][c][k] bf16 ----------------
__global__ __launch_bounds__(256) void cvt_wt_kernel(const float* __restrict__ in,
                                                     unsigned short* __restrict__ out) {
  __shared__ float tile[32][33];
  int mat = blockIdx.z;
  int k0 = blockIdx.x * 32, c0 = blockIdx.y * 32;
  int tx = threadIdx.x & 31, ty = threadIdx.x >> 5;
  const float* ip = in + mat * 16384;
  unsigned short* op = out + mat * 16384;
#pragma unroll
  for (int rr = 0; rr < 32; rr += 8)
    tile[ty + rr][tx] = ip[(k0 + ty + rr) * 128 + (c0 + tx)];
  __syncthreads();
#pragma unroll
  for (int rr = 0; rr < 32; rr += 8)
    op[(c0 + ty + rr) * 128 + (k0 + tx)] = f2bf(tile[tx][ty + rr]);
}

// ---------------- pass 1: bucket edges by dst range (both channels) ----------------
__global__ __launch_bounds__(256) void bucket_kernel(const int* __restrict__ e1,
                                                     const int* __restrict__ e2,
                                                     int* __restrict__ bcur,
                                                     uint2* __restrict__ pairs) {
  int ch = blockIdx.x >= P1B;
  int blk = blockIdx.x - ch * P1B;
  const int* E = ch ? e2 : e1;
  int base = blk * CHUNK;
  __shared__ int lcnt[NB2], gbase[NB2];
  for (int i = threadIdx.x; i < NB2; i += 256) lcnt[i] = 0;
  __syncthreads();
  int srcv[16], dstv[16], lrank[16];
#pragma unroll
  for (int k = 0; k < 16; k++) {
    int e = base + k * 256 + threadIdx.x;
    if (e < NE) {
      srcv[k] = E[e];
      dstv[k] = E[NE + e];
      lrank[k] = atomicAdd(&lcnt[dstv[k] / NPB], 1);
    } else dstv[k] = -1;
  }
  __syncthreads();
  for (int i = threadIdx.x; i < NB2; i += 256)
    gbase[i] = atomicAdd(&bcur[ch * NB2 + i], lcnt[i]);
  __syncthreads();
#pragma unroll
  for (int k = 0; k < 16; k++)
    if (dstv[k] >= 0) {
      int g = dstv[k] / NPB;
      pairs[(size_t)(ch * NB2 + g) * CAP2 + gbase[g] + lrank[k]] =
          make_uint2((unsigned)srcv[k], (unsigned)dstv[k]);
    }
}

// ---------------- per-channel exclusive scan of bucket counts (256 = 2ch x 128) ----------------
__global__ __launch_bounds__(256) void scan_bcur_kernel(const int* __restrict__ bcur,
                                                        int* __restrict__ colbase) {
  __shared__ int s[256];
  int tid = threadIdx.x;
  int v = bcur[tid];
  s[tid] = v;
  __syncthreads();
  int segstart = tid & ~127;  // don't scan across the channel boundary
  for (int o = 1; o < 128; o <<= 1) {
    int t = (tid - o >= segstart) ? s[tid - o] : 0;
    __syncthreads();
    s[tid] += t;
    __syncthreads();
  }
  colbase[tid] = s[tid] - v;
}

// ---------------- pass 2: per-bucket counting sort -> rowptr + col (no global atomics) ----------------
__global__ __launch_bounds__(256) void csr_build_kernel(const uint2* __restrict__ pairs,
                                                        const int* __restrict__ bcur,
                                                        const int* __restrict__ colbase,
                                                        int* __restrict__ rowptr,
                                                        int* __restrict__ col) {
  int g = blockIdx.x;         // 0..255 = ch*128 + bucket
  int ch = g >> 7, b = g & 127;
  int node0 = b * NPB;
  int nloc = min(NPB, NN - node0);
  int count = bcur[g];
  int base = colbase[g];
  const uint2* p = pairs + (size_t)g * CAP2;
  __shared__ int hist[512], pref[512], cur[512], stmp[256];
  for (int i = threadIdx.x; i < 512; i += 256) hist[i] = 0;
  __syncthreads();
  for (int e = threadIdx.x; e < count; e += 256)
    atomicAdd(&hist[(int)p[e].y - node0], 1);
  __syncthreads();
  int t = threadIdx.x;
  int a0 = hist[2 * t], a1 = hist[2 * t + 1];
  int sum = a0 + a1;
  stmp[t] = sum;
  __syncthreads();
  for (int o = 1; o < 256; o <<= 1) {
    int tv = (t >= o) ? stmp[t - o] : 0;
    __syncthreads();
    stmp[t] += tv;
    __syncthreads();
  }
  int ex = stmp[t] - sum;
  pref[2 * t] = ex;       pref[2 * t + 1] = ex + a0;
  cur[2 * t] = ex;        cur[2 * t + 1] = ex + a0;
  __syncthreads();
  for (int i = threadIdx.x; i < nloc; i += 256)
    rowptr[ch * (NN + 1) + node0 + i] = base + pref[i];
  if (threadIdx.x == 0 && b == NB2 - 1) rowptr[ch * (NN + 1) + NN] = base + count;
  for (int e = threadIdx.x; e < count; e += 256) {
    uint2 pr = p[e];
    int pos = atomicAdd(&cur[(int)pr.y - node0], 1);
    col[ch * NE + base + pos] = (int)pr.x;
  }
}

// ---------------- aggregation (combined 100k nodes): y = x + sum_{src->dst} x[src] ----------------
__global__ __launch_bounds__(256) void agg_kernel(const unsigned short* __restrict__ X,
                                                  const int* __restrict__ rowptr,
                                                  const int* __restrict__ col,
                                                  unsigned short* __restrict__ Y) {
  int node = blockIdx.x * 16 + (threadIdx.x >> 4);  // 0..99999
  int lane = threadIdx.x & 15;
  int ch = node >= NN;
  int nl = node - ch * NN;
  const int* rp = rowptr + ch * (NN + 1);
  const int* cl = col + ch * NE;
  const uint4* X4 = reinterpret_cast<const uint4*>(X);
  size_t chbase = (size_t)ch * NN * 16;
  float acc[8];
  {
    uint4 sv = X4[(size_t)node * 16 + lane];
    unsigned int w[4] = {sv.x, sv.y, sv.z, sv.w};
#pragma unroll
    for (int q = 0; q < 4; q++) {
      acc[2 * q]     = __uint_as_float(w[q] << 16);
      acc[2 * q + 1] = __uint_as_float(w[q] & 0xffff0000u);
    }
  }
  int s = rp[nl], e = rp[nl + 1];
  int j = s;
  for (; j + 8 <= e; j += 8) {
    uint4 v[8];
#pragma unroll
    for (int q = 0; q < 8; q++)
      v[q] = X4[chbase + (size_t)cl[j + q] * 16 + lane];
#pragma unroll
    for (int q = 0; q < 8; q++) {
      unsigned int w[4] = {v[q].x, v[q].y, v[q].z, v[q].w};
#pragma unroll
      for (int t = 0; t < 4; t++) {
        acc[2 * t]     += __uint_as_float(w[t] << 16);
        acc[2 * t + 1] += __uint_as_float(w[t] & 0xffff0000u);
      }
    }
  }
  for (; j < e; ++j) {
    uint4 v = X4[chbase + (size_t)cl[j] * 16 + lane];
    unsigned int w[4] = {v.x, v.y, v.z, v.w};
#pragma unroll
    for (int t = 0; t < 4; t++) {
      acc[2 * t]     += __uint_as_float(w[t] << 16);
      acc[2 * t + 1] += __uint_as_float(w[t] & 0xffff0000u);
    }
  }
  uint4 o;
  unsigned int* ow = reinterpret_cast<unsigned int*>(&o);
#pragma unroll
  for (int q = 0; q < 4; q++)
    ow[q] = (unsigned int)f2bf(acc[2 * q]) | ((unsigned int)f2bf(acc[2 * q + 1]) << 16);
  reinterpret_cast<uint4*>(Y)[(size_t)node * 16 + lane] = o;
}

// ---------------- fused layer: out = act2(act1(Y@W1+b1)@W2+b2), + pool into z ----------------
__global__ __launch_bounds__(256) void gemm_fused_kernel(
    const unsigned short* __restrict__ Y, unsigned short* __restrict__ X,
    const unsigned short* __restrict__ WT,
    const float* __restrict__ b1c1, const float* __restrict__ b1c2,
    const float* __restrict__ b2c1, const float* __restrict__ b2c2,
    const float* __restrict__ bng, const float* __restrict__ bnb,
    const float* __restrict__ bnm, const float* __restrict__ bnv,
    const int* __restrict__ batch1, const int* __restrict__ batch2,
    float* __restrict__ z, int layer) {
  __shared__ unsigned short hlds[16][136];
  int ch = blockIdx.x >= 1024;
  int lane = threadIdx.x & 63, wv = threadIdx.x >> 6;
  int l15 = lane & 15, lk = lane >> 4;
  int c0 = wv * 32;
  const unsigned short* W1 = WT + (size_t)(ch * 6 + layer) * 16384;
  const unsigned short* W2 = WT + (size_t)(ch * 6 + 3 + layer) * 16384;
  short8 w1f[2][4], w2f[2][4];
#pragma unroll
  for (int ct = 0; ct < 2; ct++)
#pragma unroll
    for (int kk = 0; kk < 4; kk++) {
      size_t boff = (size_t)(c0 + ct * 16 + l15) * 128 + kk * 32 + lk * 8;
      w1f[ct][kk] = *reinterpret_cast<const short8*>(W1 + boff);
      w2f[ct][kk] = *reinterpret_cast<const short8*>(W2 + boff);
    }
  const float* b1 = (ch ? b1c2 : b1c1) + layer * DD;
  const float* b2 = (ch ? b2c2 : b2c1) + layer * DD;
  const int* batch = ch ? batch2 : batch1;
  float sc1[2], sh1[2], sh2[2];
#pragma unroll
  for (int ct = 0; ct < 2; ct++) {
    int colg = c0 + ct * 16 + l15;
    if (!ch) {
      float s = bng[layer * DD + colg] * rsqrtf(bnv[layer * DD + colg] + 1e-5f);
      sc1[ct] = s;
      sh1[ct] = (b1[colg] - bnm[layer * DD + colg]) * s + bnb[layer * DD + colg];
    } else {
      sc1[ct] = 1.f;
      sh1[ct] = b1[colg];
    }
    sh2[ct] = b2[colg];
  }
  for (int t = (ch ? blockIdx.x - 1024 : blockIdx.x); t < 3125; t += 1024) {
    int r0l = t * 16;
    size_t r0g = (size_t)ch * NN + r0l;
    const unsigned short* yp = Y + (r0g + l15) * 128 + lk * 8;
    short8 a0 = *reinterpret_cast<const short8*>(yp);
    short8 a1 = *reinterpret_cast<const short8*>(yp + 32);
    short8 a2 = *reinterpret_cast<const short8*>(yp + 64);
    short8 a3 = *reinterpret_cast<const short8*>(yp + 96);
#pragma unroll
    for (int ct = 0; ct < 2; ct++) {
      f32x4 acc = {0.f, 0.f, 0.f, 0.f};
      acc = __builtin_amdgcn_mfma_f32_16x16x32_bf16(a0, w1f[ct][0], acc, 0, 0, 0);
      acc = __builtin_amdgcn_mfma_f32_16x16x32_bf16(a1, w1f[ct][1], acc, 0, 0, 0);
      acc = __builtin_amdgcn_mfma_f32_16x16x32_bf16(a2, w1f[ct][2], acc, 0, 0, 0);
      acc = __builtin_amdgcn_mfma_f32_16x16x32_bf16(a3, w1f[ct][3], acc, 0, 0, 0);
      int colg = c0 + ct * 16 + l15;
#pragma unroll
      for (int r = 0; r < 4; r++) {
        float tv = fmaxf(acc[r] * sc1[ct] + sh1[ct], 0.f);
        hlds[lk * 4 + r][colg] = f2bf(tv);
      }
    }
    __syncthreads();
    short8 h0 = *reinterpret_cast<const short8*>(&hlds[l15][lk * 8]);
    short8 h1 = *reinterpret_cast<const short8*>(&hlds[l15][32 + lk * 8]);
    short8 h2 = *reinterpret_cast<const short8*>(&hlds[l15][64 + lk * 8]);
    short8 h3 = *reinterpret_cast<const short8*>(&hlds[l15][96 + lk * 8]);
#pragma unroll
    for (int ct = 0; ct < 2; ct++) {
      f32x4 acc = {0.f, 0.f, 0.f, 0.f};
      acc = __builtin_amdgcn_mfma_f32_16x16x32_bf16(h0, w2f[ct][0], acc, 0, 0, 0);
      acc = __builtin_amdgcn_mfma_f32_16x16x32_bf16(h1, w2f[ct][1], acc, 0, 0, 0);
      acc = __builtin_amdgcn_mfma_f32_16x16x32_bf16(h2, w2f[ct][2], acc, 0, 0, 0);
      acc = __builtin_amdgcn_mfma_f32_16x16x32_bf16(h3, w2f[ct][3], acc, 0, 0, 0);
      int colg = c0 + ct * 16 + l15;
      float v[4];
#pragma unroll
      for (int r = 0; r < 4; r++) {
        float tv = acc[r] + sh2[ct];
        if (!ch) tv = fmaxf(tv, 0.f);
        else     tv = tv > 0.f ? tv : 0.01f * tv;
        v[r] = tv;
        X[(r0g + lk * 4 + r) * 128 + colg] = f2bf(tv);
      }
      int zc = ch * (DD * NL) + layer * DD + colg;
      int g0 = batch[r0l], g15 = batch[r0l + 15];
      if (g0 == g15) {
        float s = v[0] + v[1] + v[2] + v[3];
        s += __shfl_xor(s, 16);
        s += __shfl_xor(s, 32);
        if (lk == 0) atomicAdd(&z[(size_t)g0 * ZW + zc], s);
      } else {
#pragma unroll
        for (int r = 0; r < 4; r++)
          atomicAdd(&z[(size_t)batch[r0l + lk * 4 + r] * ZW + zc], v[r]);
      }
    }
    __syncthreads();
  }
}

// ---------------- head: relu(z @ Wf1 + bf1) @ Wf2 + bf2 ----------------
__global__ __launch_bounds__(128) void head_kernel(const float* __restrict__ z,
                                                   const float* __restrict__ Wf1,
                                                   const float* __restrict__ bf1,
                                                   const float* __restrict__ Wf2,
                                                   const float* __restrict__ bf2,
                                                   float* __restrict__ out) {
  int g = blockIdx.x, t = threadIdx.x;
  const float* zr = z + (size_t)g * ZW;
  float acc = bf1[t];
  for (int j = 0; j < ZW; ++j) acc += zr[j] * Wf1[(size_t)j * DD + t];
  float h = fmaxf(acc, 0.f);
  __shared__ float red[128];
  red[t] = h * Wf2[t];
  __syncthreads();
  for (int s = 64; s > 0; s >>= 1) {
    if (t < s) red[t] += red[t + s];
    __syncthreads();
  }
  if (t == 0) out[g] = red[0] + bf2[0];
}

extern "C" void kernel_launch(void* const* d_in, const int* in_sizes, int n_in,
                              void* d_out, int out_size, void* d_ws, size_t ws_size,
                              hipStream_t stream) {
  const float* x1   = (const float*)d_in[0];
  const float* x2   = (const float*)d_in[1];
  const float* W1c1 = (const float*)d_in[2];
  const float* b1c1 = (const float*)d_in[3];
  const float* bng  = (const float*)d_in[4];
  const float* bnb  = (const float*)d_in[5];
  const float* bnm  = (const float*)d_in[6];
  const float* bnv  = (const float*)d_in[7];
  const float* W2c1 = (const float*)d_in[8];
  const float* b2c1 = (const float*)d_in[9];
  const float* W1c2 = (const float*)d_in[10];
  const float* b1c2 = (const float*)d_in[11];
  const float* W2c2 = (const float*)d_in[12];
  const float* b2c2 = (const float*)d_in[13];
  const float* Wf1  = (const float*)d_in[14];
  const float* bf1  = (const float*)d_in[15];
  const float* Wf2  = (const float*)d_in[16];
  const float* bf2  = (const float*)d_in[17];
  const int* edge1  = (const int*)d_in[18];
  const int* edge2  = (const int*)d_in[19];
  const int* batch1 = (const int*)d_in[20];
  const int* batch2 = (const int*)d_in[21];
  (void)ws_size; (void)n_in; (void)in_sizes; (void)out_size;

  char* ws = (char*)d_ws;
  const size_t NB16 = (size_t)2 * NN * DD * 2;  // 25.6 MB combined node buffer
  unsigned short* bufX = (unsigned short*)(ws);
  unsigned short* bufY = (unsigned short*)(ws + NB16);
  size_t off = 2 * NB16;
  unsigned short* WT = (unsigned short*)(ws + off); off += (size_t)12 * 16384 * 2;
  uint2* pairs = (uint2*)(ws + off); off += (size_t)2 * NB2 * CAP2 * 8;
  int* col     = (int*)(ws + off); off += (size_t)2 * NE * 4;
  int* rowptr  = (int*)(ws + off); off += (((size_t)2 * (NN + 1) * 4) + 255) & ~(size_t)255;
  int* bcur    = (int*)(ws + off); off += 256 * 4;
  int* colbase = (int*)(ws + off); off += 256 * 4;
  float* z     = (float*)(ws + off); off += (size_t)NG * ZW * 4;

  // weights: fp32 [k][c] -> bf16 [c][k], 12 matrices
  cvt_wt_kernel<<<dim3(4, 4, 3), 256, 0, stream>>>(W1c1, WT + 0 * 16384);
  cvt_wt_kernel<<<dim3(4, 4, 3), 256, 0, stream>>>(W2c1, WT + 3 * 16384);
  cvt_wt_kernel<<<dim3(4, 4, 3), 256, 0, stream>>>(W1c2, WT + 6 * 16384);
  cvt_wt_kernel<<<dim3(4, 4, 3), 256, 0, stream>>>(W2c2, WT + 9 * 16384);

  hipMemsetAsync(z, 0, (size_t)NG * ZW * 4, stream);
  hipMemsetAsync(bcur, 0, 256 * 4, stream);

  cvt_bf16_kernel<<<(NN * DD / 8 + 255) / 256, 256, 0, stream>>>(x1, bufX, NN * DD / 8);
  cvt_bf16_kernel<<<(NN * DD / 8 + 255) / 256, 256, 0, stream>>>(x2, bufX + (size_t)NN * DD,
                                                                 NN * DD / 8);

  // CSR build (both channels), no global atomics in the hot paths
  bucket_kernel<<<2 * P1B, 256, 0, stream>>>(edge1, edge2, bcur, pairs);
  scan_bcur_kernel<<<1, 256, 0, stream>>>(bcur, colbase);
  csr_build_kernel<<<2 * NB2, 256, 0, stream>>>(pairs, bcur, colbase, rowptr, col);

  for (int i = 0; i < NL; ++i) {
    agg_kernel<<<2 * NN / 16, 256, 0, stream>>>(bufX, rowptr, col, bufY);
    gemm_fused_kernel<<<2048, 256, 0, stream>>>(bufY, bufX, WT,
                                                b1c1, b1c2, b2c1, b2c2,
                                                bng, bnb, bnm, bnv,
                                                batch1, batch2, z, i);
  }
  head_kernel<<<NG, 128, 0, stream>>>(z, Wf1, bf1, Wf2, bf2, (float*)d_out);
}